// Round 2
// baseline (178.769 us; speedup 1.0000x reference)
//
#include <hip/hip_runtime.h>
#include <math.h>

// EdgeDetection: fused gray -> gauss3x3(sigma=0.8) -> scharr -> L2 mag, reflect-101
// R2: single-barrier version. Gauss∘Scharr composed into separable 5-tap kernels:
//   sx = (vertical [3,10,3]*g) x (horizontal [-1,0,1]*g)
//   sy = (vertical [-1,0,1]*g) x (horizontal [3,10,3]*g)
// One LDS array (gray only), 128x32 tile, 16 px/thread, deep staging load pipeline.
// R3: output stores nontemporal (write-once stream; keep L2 for input halo reuse).
// R4: nontemporal store via clang ext_vector_type (HIP float4 class rejected by builtin).

#define IMG_H 1024
#define IMG_W 1024
#define TH 32
#define TW 128
#define GYR (TH + 4)      // 36 gray rows  (y0-2 .. y0+33)
#define GXD 136           // gray cols = stride (x0-4 .. x0+131), 136*4 B = 16B-mult
#define NIT ((GYR * (GXD/4) + 255) / 256)   // 5 staging iterations
#define NITEMS (GYR * (GXD/4))              // 1224

// 1D gaussian sigma=0.8 k=3: e=exp(-0.78125); W0=1/(1+2e), W1=e/(1+2e)
#define W0 0.52201125f
#define W1 0.23899437f
// composite smooth taps a = conv([3,10,3],[W1,W0,W1]) (symmetric):
#define AV0 0.71698311f   // 3*W1
#define AV1 3.95597745f   // 3*W0 + 10*W1
#define AV2 6.65407872f   // 10*W0 + 6*W1
// composite deriv taps d = conv([-1,0,1],[W1,W0,W1]) = [-W1,-W0,0,W0,W1]

typedef float vf4 __attribute__((ext_vector_type(4)));

__device__ __forceinline__ int reflect101(int v, int n) {
    v = (v < 0) ? -v : v;
    return (v >= n) ? (2 * n - 2 - v) : v;
}

__global__ __launch_bounds__(256)
void edge_kernel(const float* __restrict__ in, float* __restrict__ out, int B) {
    __shared__ float sg[GYR][GXD];

    const int tid = threadIdx.x;
    const int x0 = blockIdx.x * TW;
    const int y0 = blockIdx.y * TH;
    const int b  = blockIdx.z;

    const size_t plane = (size_t)IMG_H * IMG_W;
    const float* pr = in + (size_t)b * 3 * plane;
    const float* pg = pr + plane;
    const float* pb = pg + plane;

    // ---- stage gray tile: two-phase (issue all loads, then convert+write) ----
    float4 R[NIT], G[NIT], Bv[NIT];
    #pragma unroll
    for (int it = 0; it < NIT; ++it) {
        int i = tid + it * 256;
        if (i < NITEMS) {
            int gy  = i / (GXD / 4);
            int gx4 = (i - gy * (GXD / 4)) * 4;
            int y = reflect101(y0 - 2 + gy, IMG_H);
            int x = x0 - 4 + gx4;
            if ((unsigned)x <= (unsigned)(IMG_W - 4)) {
                size_t o = (size_t)y * IMG_W + x;
                R[it]  = *(const float4*)(pr + o);
                G[it]  = *(const float4*)(pg + o);
                Bv[it] = *(const float4*)(pb + o);
            } else {
                int xe0 = reflect101(x,     IMG_W), xe1 = reflect101(x + 1, IMG_W);
                int xe2 = reflect101(x + 2, IMG_W), xe3 = reflect101(x + 3, IMG_W);
                size_t ro = (size_t)y * IMG_W;
                R[it]  = make_float4(pr[ro+xe0], pr[ro+xe1], pr[ro+xe2], pr[ro+xe3]);
                G[it]  = make_float4(pg[ro+xe0], pg[ro+xe1], pg[ro+xe2], pg[ro+xe3]);
                Bv[it] = make_float4(pb[ro+xe0], pb[ro+xe1], pb[ro+xe2], pb[ro+xe3]);
            }
        }
    }
    #pragma unroll
    for (int it = 0; it < NIT; ++it) {
        int i = tid + it * 256;
        if (i < NITEMS) {
            int gy  = i / (GXD / 4);
            int gx4 = (i - gy * (GXD / 4)) * 4;
            float4 gr;
            gr.x = 0.299f * R[it].x + 0.587f * G[it].x + 0.114f * Bv[it].x;
            gr.y = 0.299f * R[it].y + 0.587f * G[it].y + 0.114f * Bv[it].y;
            gr.z = 0.299f * R[it].z + 0.587f * G[it].z + 0.114f * Bv[it].z;
            gr.w = 0.299f * R[it].w + 0.587f * G[it].w + 0.114f * Bv[it].w;
            *(float4*)&sg[gy][gx4] = gr;
        }
    }
    __syncthreads();

    // ---- compute: each thread does 4 rows x 4 cols via 5-row (hs,hd) ring ----
    const int tx  = tid & 31;       // col group
    const int tyg = tid >> 5;       // 0..7
    const int c4  = tx * 4;         // output cols x0+c4 .. x0+c4+3
    const int r0  = tyg * 4;        // output rows y0+r0 .. y0+r0+3

    float hs[5][4], hd[5][4];

    auto hrow = [&](int rr, float* HS, float* HD) {
        const float* row = &sg[rr][c4];
        float4 ga = *(const float4*)(row);
        float4 gb = *(const float4*)(row + 4);
        float4 gc = *(const float4*)(row + 8);
        float g[12] = {ga.x, ga.y, ga.z, ga.w, gb.x, gb.y, gb.z, gb.w,
                       gc.x, gc.y, gc.z, gc.w};
        #pragma unroll
        for (int k = 0; k < 4; ++k) {
            HS[k] = AV0 * (g[k+2] + g[k+6]) + AV1 * (g[k+3] + g[k+5]) + AV2 * g[k+4];
            HD[k] = W1 * (g[k+6] - g[k+2]) + W0 * (g[k+5] - g[k+3]);
        }
    };

    #pragma unroll
    for (int s = 0; s < 5; ++s) hrow(r0 + s, hs[s], hd[s]);

    float* po = out + (size_t)b * 3 * plane;
    #pragma unroll
    for (int t = 0; t < 4; ++t) {
        if (t > 0) hrow(r0 + 4 + t, hs[(t + 4) % 5], hd[(t + 4) % 5]);
        const int i0 = t % 5, i1 = (t+1) % 5, i2 = (t+2) % 5, i3 = (t+3) % 5, i4 = (t+4) % 5;
        vf4 mag;
        #pragma unroll
        for (int k = 0; k < 4; ++k) {
            float sx = AV0 * (hd[i0][k] + hd[i4][k]) + AV1 * (hd[i1][k] + hd[i3][k]) + AV2 * hd[i2][k];
            float sy = W1 * (hs[i4][k] - hs[i0][k]) + W0 * (hs[i3][k] - hs[i1][k]);
            mag[k] = sqrtf(sx * sx + sy * sy);
        }
        size_t o = (size_t)(y0 + r0 + t) * IMG_W + (x0 + c4);
        __builtin_nontemporal_store(mag, (vf4*)(po + o));
        __builtin_nontemporal_store(mag, (vf4*)(po + o + plane));
        __builtin_nontemporal_store(mag, (vf4*)(po + o + 2 * plane));
    }
}

extern "C" void kernel_launch(void* const* d_in, const int* in_sizes, int n_in,
                              void* d_out, int out_size, void* d_ws, size_t ws_size,
                              hipStream_t stream) {
    const float* in = (const float*)d_in[0];
    float* out = (float*)d_out;
    const int B = in_sizes[0] / (3 * IMG_H * IMG_W);
    dim3 grid(IMG_W / TW, IMG_H / TH, B);
    edge_kernel<<<grid, dim3(256), 0, stream>>>(in, out, B);
}